// Round 1
// baseline (2366.555 us; speedup 1.0000x reference)
//
#include <hip/hip_runtime.h>
#include <math.h>

// BinaryTreeLSTM — fp32 baseline.
// Key algebraic reductions vs reference:
//  * gates[:, keep] only needs 512 of 1024 weight rows (cols 128..255 of each
//    gate are discarded by h2[:, :H]) -> halves the GEMM.
//  * c0[:, :128] is the LEFT child's c only -> right-child c never re-read.
//  * top level (d=17) has h0=c0=0 -> skip the K=256 recurrent phase.
// Packed B layout: Bp[k][4*j+g] = W[g*256+j][k] (g: 0=i,1=f,2=g,3=o), so a
// 128-wide N-tile covers 32 output columns with all four gates adjacent ->
// elementwise epilogue is register-local per thread.

#define NIN 128
#define HID 128
#define KTOT 384
#define NP 512
#define TM 64
#define TN 128
#define KC 32

__global__ __launch_bounds__(256) void pack_weights(
    const float* __restrict__ W_ih, const float* __restrict__ W_hh,
    const float* __restrict__ b_ih, const float* __restrict__ b_hh,
    float* __restrict__ Bp, float* __restrict__ biasp)
{
    int idx = blockIdx.x * 256 + threadIdx.x;
    if (idx < KTOT * NP) {
        int k = idx / NP, cc = idx - k * NP;
        int j = cc >> 2, g = cc & 3;
        int r = g * 256 + j;                 // live row in original W
        float v = (k < NIN) ? W_ih[(size_t)r * NIN + k]
                            : W_hh[(size_t)r * 256 + (k - NIN)];
        Bp[idx] = v;
    }
    if (idx < NP) {
        int j = idx >> 2, g = idx & 3;
        int r = g * 256 + j;
        biasp[idx] = b_ih[r] + b_hh[r];
    }
}

__device__ __forceinline__ float sigf(float x) { return 1.f / (1.f + expf(-x)); }

__global__ __launch_bounds__(256) void level_kernel(
    const float* __restrict__ emb,
    const float* __restrict__ Bp, const float* __restrict__ biasp,
    const float* __restrict__ h_in,   // child h: (2n,128) flat; null if top
    const float* __restrict__ c_in,   // child c
    float* __restrict__ h_out,        // (n,128)
    float* __restrict__ c_out,
    int n, int isTop)
{
    __shared__ float As[TM][36];      // +4 pad keeps 16B alignment, breaks stride
    __shared__ float Bs[KC][TN];

    const int tid = threadIdx.x;
    const int tx = tid & 31, ty = tid >> 5;
    const int row0 = blockIdx.x * TM;
    const int by = blockIdx.y;

    float acc[8][4];
    #pragma unroll
    for (int r = 0; r < 8; ++r)
        #pragma unroll
        for (int c = 0; c < 4; ++c) acc[r][c] = 0.f;

    // ---- Phase 1: K = 0..127 from embeddings[n-1 + node] ----
    for (int kc = 0; kc < NIN; kc += KC) {
        {
            int m = tid >> 2;
            int kk = (tid & 3) * 8;
            int node = row0 + m;
            float4 a0 = make_float4(0, 0, 0, 0), a1 = a0;
            if (node < n) {
                const float* p = emb + (size_t)(n - 1 + node) * NIN + kc + kk;
                a0 = *(const float4*)p;
                a1 = *(const float4*)(p + 4);
            }
            *(float4*)&As[m][kk] = a0;
            *(float4*)&As[m][kk + 4] = a1;
        }
        {
            int c = tx * 4;
            #pragma unroll
            for (int p = 0; p < 4; ++p) {
                int k = ty + p * 8;
                *(float4*)&Bs[k][c] =
                    *(const float4*)(Bp + (size_t)(kc + k) * NP + by * TN + c);
            }
        }
        __syncthreads();
        #pragma unroll
        for (int k4 = 0; k4 < KC / 4; ++k4) {
            float4 b0 = *(float4*)&Bs[k4 * 4 + 0][tx * 4];
            float4 b1 = *(float4*)&Bs[k4 * 4 + 1][tx * 4];
            float4 b2 = *(float4*)&Bs[k4 * 4 + 2][tx * 4];
            float4 b3 = *(float4*)&Bs[k4 * 4 + 3][tx * 4];
            #pragma unroll
            for (int r = 0; r < 8; ++r) {
                float4 a = *(float4*)&As[ty * 8 + r][k4 * 4];
                acc[r][0] += a.x * b0.x + a.y * b1.x + a.z * b2.x + a.w * b3.x;
                acc[r][1] += a.x * b0.y + a.y * b1.y + a.z * b2.y + a.w * b3.y;
                acc[r][2] += a.x * b0.z + a.y * b1.z + a.z * b2.z + a.w * b3.z;
                acc[r][3] += a.x * b0.w + a.y * b1.w + a.z * b2.w + a.w * b3.w;
            }
        }
        __syncthreads();
    }

    // ---- Phase 2: K = 128..383 from child h (contiguous (n,256) view) ----
    if (!isTop) {
        for (int kc = 0; kc < 256; kc += KC) {
            {
                int m = tid >> 2;
                int kk = (tid & 3) * 8;
                int node = row0 + m;
                float4 a0 = make_float4(0, 0, 0, 0), a1 = a0;
                if (node < n) {
                    const float* p = h_in + (size_t)node * 256 + kc + kk;
                    a0 = *(const float4*)p;
                    a1 = *(const float4*)(p + 4);
                }
                *(float4*)&As[m][kk] = a0;
                *(float4*)&As[m][kk + 4] = a1;
            }
            {
                int c = tx * 4;
                #pragma unroll
                for (int p = 0; p < 4; ++p) {
                    int k = ty + p * 8;
                    *(float4*)&Bs[k][c] =
                        *(const float4*)(Bp + (size_t)(NIN + kc + k) * NP + by * TN + c);
                }
            }
            __syncthreads();
            #pragma unroll
            for (int k4 = 0; k4 < KC / 4; ++k4) {
                float4 b0 = *(float4*)&Bs[k4 * 4 + 0][tx * 4];
                float4 b1 = *(float4*)&Bs[k4 * 4 + 1][tx * 4];
                float4 b2 = *(float4*)&Bs[k4 * 4 + 2][tx * 4];
                float4 b3 = *(float4*)&Bs[k4 * 4 + 3][tx * 4];
                #pragma unroll
                for (int r = 0; r < 8; ++r) {
                    float4 a = *(float4*)&As[ty * 8 + r][k4 * 4];
                    acc[r][0] += a.x * b0.x + a.y * b1.x + a.z * b2.x + a.w * b3.x;
                    acc[r][1] += a.x * b0.y + a.y * b1.y + a.z * b2.y + a.w * b3.y;
                    acc[r][2] += a.x * b0.z + a.y * b1.z + a.z * b2.z + a.w * b3.z;
                    acc[r][3] += a.x * b0.w + a.y * b1.w + a.z * b2.w + a.w * b3.w;
                }
            }
            __syncthreads();
        }
    }

    // ---- Epilogue: i,f,g,o for 32 output cols live in-register ----
    const int j = by * 32 + tx;
    const float4 bb = *(const float4*)(biasp + by * TN + tx * 4);
    #pragma unroll
    for (int r = 0; r < 8; ++r) {
        int node = row0 + ty * 8 + r;
        if (node < n) {
            float gi = acc[r][0] + bb.x;
            float gf = acc[r][1] + bb.y;
            float gg = acc[r][2] + bb.z;
            float go = acc[r][3] + bb.w;
            float cl = isTop ? 0.f : c_in[(size_t)node * 256 + j]; // left child c
            float cn = sigf(gf) * cl + sigf(gi) * tanhf(gg);
            float hn = sigf(go) * tanhf(cn);
            h_out[(size_t)node * HID + j] = hn;
            c_out[(size_t)node * HID + j] = cn;
        }
    }
}

extern "C" void kernel_launch(void* const* d_in, const int* in_sizes, int n_in,
                              void* d_out, int out_size, void* d_ws, size_t ws_size,
                              hipStream_t stream) {
    const float* emb  = (const float*)d_in[0];
    const float* W_ih = (const float*)d_in[1];
    const float* W_hh = (const float*)d_in[2];
    const float* b_ih = (const float*)d_in[3];
    const float* b_hh = (const float*)d_in[4];
    float* out = (float*)d_out;
    float* ws = (float*)d_ws;

    const size_t BUF = (size_t)131072 * 128;            // max level rows x 128
    const size_t offBp = 0;
    const size_t offBias = (size_t)KTOT * NP;           // 196608
    const size_t offBufs = offBias + NP;                // 197120
    const size_t need = (offBufs + 4 * BUF) * sizeof(float);
    if (ws_size < need) return;  // fail loudly (wrong output) rather than UB

    float* Bp = ws + offBp;
    float* biasp = ws + offBias;
    float* hbuf[2] = { ws + offBufs, ws + offBufs + BUF };
    float* cbuf[2] = { ws + offBufs + 2 * BUF, ws + offBufs + 3 * BUF };

    pack_weights<<<(KTOT * NP + 255) / 256, 256, 0, stream>>>(
        W_ih, W_hh, b_ih, b_hh, Bp, biasp);

    int wr = 0;
    for (int d = 17; d >= 0; --d) {
        int n = 1 << d;
        int isTop = (d == 17);
        const float* hin = isTop ? nullptr : hbuf[wr ^ 1];
        const float* cin = isTop ? nullptr : cbuf[wr ^ 1];
        float* ho = (d == 0) ? out : hbuf[wr];
        float* co = (d == 0) ? out + HID : cbuf[wr];
        dim3 grid((n + TM - 1) / TM, 4);
        level_kernel<<<grid, 256, 0, stream>>>(emb, Bp, biasp, hin, cin, ho, co, n, isTop);
        wr ^= 1;
    }
}

// Round 2
// 787.214 us; speedup vs baseline: 3.0062x; 3.0062x over previous
//
#include <hip/hip_runtime.h>
#include <math.h>

// BinaryTreeLSTM — round 2: bf16x3 split-precision MFMA.
// C[n x 512] = A[n x 384] * Bp[384 x 512] per level, where
//   A = [emb_level (K 0..127) | child h pairs (K 128..383)]
//   Bp packed so cols = g*32 + jl (gate-major blocks of 32 j's) per by-tile,
//   in MFMA B-fragment order [by][kc][col][k] -> staging is a straight copy.
// Split each operand x = hi + lo (bf16 each); acc += aL*bH + aH*bL + aH*bH
// gives ~2^-17 relative error (fp32-class), 3 MFMA per logical tile.
// Wave tile 64x64 = 4x4 frags of 16x16x32; gate index == N-fragment index so
// the i,f,g,o gates of output column j are register-local in one lane.

typedef __bf16 bf16x8 __attribute__((ext_vector_type(8)));
typedef float f32x4 __attribute__((ext_vector_type(4)));

#define HID 128
#define TM 128
#define LDST 40   // padded LDS row stride (32 data + 8 pad) -> 80 B, 20 banks

__device__ __forceinline__ float sigf(float x) { return 1.f / (1.f + expf(-x)); }

__device__ __forceinline__ void split_bf16(float f, __bf16& h, __bf16& l) {
    __bf16 hh = (__bf16)f;
    h = hh;
    l = (__bf16)(f - (float)hh);
}

// Pack W_ih|W_hh live rows (512 of 1024) into hi/lo bf16 planes in fragment
// order: idx = ((by*12 + kci)*128 + c)*32 + k, c = g*32 + jl,
// original row = g*256 + by*32 + jl, original k = kci*32 + k.
__global__ __launch_bounds__(256) void pack_weights(
    const float* __restrict__ W_ih, const float* __restrict__ W_hh,
    const float* __restrict__ b_ih, const float* __restrict__ b_hh,
    __bf16* __restrict__ BpH, __bf16* __restrict__ BpL,
    float* __restrict__ biasP)
{
    int idx = blockIdx.x * 256 + threadIdx.x;
    if (idx < 4 * 12 * 128 * 32) {
        int by = idx / 49152;
        int r1 = idx - by * 49152;
        int kci = r1 >> 12;
        int r2 = r1 & 4095;
        int c = r2 >> 5;
        int k = r2 & 31;
        int g = c >> 5, jl = c & 31;
        int rOrig = g * 256 + by * 32 + jl;
        int kk = kci * 32 + k;
        float w = (kk < 128) ? W_ih[(size_t)rOrig * 128 + kk]
                             : W_hh[(size_t)rOrig * 256 + (kk - 128)];
        __bf16 h, l;
        split_bf16(w, h, l);
        BpH[idx] = h;
        BpL[idx] = l;
    }
    if (idx < 512) {
        int by = idx >> 7, c = idx & 127;
        int g = c >> 5, jl = c & 31;
        int rOrig = g * 256 + by * 32 + jl;
        biasP[idx] = b_ih[rOrig] + b_hh[rOrig];
    }
}

__global__ __launch_bounds__(256) void level_mfma(
    const float* __restrict__ emb,
    const __bf16* __restrict__ BpH, const __bf16* __restrict__ BpL,
    const float* __restrict__ biasP,
    const float* __restrict__ h_in,   // child h: (2n,128) fp32 = (n,256) flat
    const float* __restrict__ c_in,   // child c
    float* __restrict__ h_out,        // (n,128) fp32
    float* __restrict__ c_out,
    int n, int isTop)
{
    __shared__ __align__(16) __bf16 AsH[TM][LDST], AsL[TM][LDST];
    __shared__ __align__(16) __bf16 BsH[128][LDST], BsL[128][LDST];

    const int tid = threadIdx.x;
    const int lane = tid & 63;
    const int w = tid >> 6;
    const int wm = w & 1, wn = w >> 1;
    const int row0 = blockIdx.x * TM;
    const int by = blockIdx.y;
    const int l15 = lane & 15;
    const int kq = lane >> 4;         // 0..3
    const int kk0 = kq * 8;

    // A staging role: 2 threads per row, 16 floats each
    const int sm = tid >> 1;
    const int sh = tid & 1;

    f32x4 acc[4][4];
    #pragma unroll
    for (int a = 0; a < 4; ++a)
        #pragma unroll
        for (int b = 0; b < 4; ++b)
            acc[a][b] = (f32x4)0.f;

    const int nch = isTop ? 4 : 12;
    for (int kci = 0; kci < nch; ++kci) {
        // ---- A tile: 128 rows x 32 k fp32 -> hi/lo bf16 in LDS ----
        {
            int node = row0 + sm;
            float vv[16];
            if (node < n) {
                const float* p = (kci < 4)
                    ? emb + (size_t)(n - 1 + node) * 128 + kci * 32 + sh * 16
                    : h_in + (size_t)node * 256 + (kci - 4) * 32 + sh * 16;
                *(float4*)(vv + 0)  = *(const float4*)(p + 0);
                *(float4*)(vv + 4)  = *(const float4*)(p + 4);
                *(float4*)(vv + 8)  = *(const float4*)(p + 8);
                *(float4*)(vv + 12) = *(const float4*)(p + 12);
            } else {
                #pragma unroll
                for (int i = 0; i < 16; ++i) vv[i] = 0.f;
            }
            __bf16 hh[16], ll[16];
            #pragma unroll
            for (int i = 0; i < 16; ++i) split_bf16(vv[i], hh[i], ll[i]);
            *(bf16x8*)&AsH[sm][sh * 16 + 0] = *(bf16x8*)&hh[0];
            *(bf16x8*)&AsH[sm][sh * 16 + 8] = *(bf16x8*)&hh[8];
            *(bf16x8*)&AsL[sm][sh * 16 + 0] = *(bf16x8*)&ll[0];
            *(bf16x8*)&AsL[sm][sh * 16 + 8] = *(bf16x8*)&ll[8];
        }
        // ---- B tile: straight copy of pre-packed 128x32 hi/lo ----
        {
            size_t base = ((size_t)(by * 12 + kci)) << 12;
            #pragma unroll
            for (int rep = 0; rep < 2; ++rep) {
                int i = rep * 256 + tid;
                int c = i >> 2, k8 = (i & 3) * 8;
                *(bf16x8*)&BsH[c][k8] = *(const bf16x8*)(BpH + base + (size_t)i * 8);
                *(bf16x8*)&BsL[c][k8] = *(const bf16x8*)(BpL + base + (size_t)i * 8);
            }
        }
        __syncthreads();

        // ---- fragments + 16 logical MFMAs x3 ----
        bf16x8 aH[4], aL[4], bH[4], bL[4];
        #pragma unroll
        for (int mi = 0; mi < 4; ++mi) {
            int rm = wm * 64 + mi * 16 + l15;
            aH[mi] = *(const bf16x8*)&AsH[rm][kk0];
            aL[mi] = *(const bf16x8*)&AsL[rm][kk0];
        }
        #pragma unroll
        for (int g = 0; g < 4; ++g) {
            int cc = g * 32 + wn * 16 + l15;
            bH[g] = *(const bf16x8*)&BsH[cc][kk0];
            bL[g] = *(const bf16x8*)&BsL[cc][kk0];
        }
        #pragma unroll
        for (int mi = 0; mi < 4; ++mi)
            #pragma unroll
            for (int g = 0; g < 4; ++g) {
                acc[mi][g] = __builtin_amdgcn_mfma_f32_16x16x32_bf16(aL[mi], bH[g], acc[mi][g], 0, 0, 0);
                acc[mi][g] = __builtin_amdgcn_mfma_f32_16x16x32_bf16(aH[mi], bL[g], acc[mi][g], 0, 0, 0);
                acc[mi][g] = __builtin_amdgcn_mfma_f32_16x16x32_bf16(aH[mi], bH[g], acc[mi][g], 0, 0, 0);
            }
        __syncthreads();
    }

    // ---- Epilogue: gates i,f,g,o register-local per lane ----
    const int j = by * 32 + wn * 16 + l15;
    const float bi = biasP[by * 128 + 0 * 32 + wn * 16 + l15];
    const float bfv = biasP[by * 128 + 1 * 32 + wn * 16 + l15];
    const float bg = biasP[by * 128 + 2 * 32 + wn * 16 + l15];
    const float bo = biasP[by * 128 + 3 * 32 + wn * 16 + l15];
    #pragma unroll
    for (int mi = 0; mi < 4; ++mi) {
        #pragma unroll
        for (int r = 0; r < 4; ++r) {
            int node = row0 + wm * 64 + mi * 16 + kq * 4 + r;
            if (node < n) {
                float gi = acc[mi][0][r] + bi;
                float gf = acc[mi][1][r] + bfv;
                float gg = acc[mi][2][r] + bg;
                float go = acc[mi][3][r] + bo;
                float cl = isTop ? 0.f : c_in[(size_t)node * 256 + j]; // left child c
                float cn = sigf(gf) * cl + sigf(gi) * tanhf(gg);
                float hn = sigf(go) * tanhf(cn);
                h_out[(size_t)node * 128 + j] = hn;
                c_out[(size_t)node * 128 + j] = cn;
            }
        }
    }
}

extern "C" void kernel_launch(void* const* d_in, const int* in_sizes, int n_in,
                              void* d_out, int out_size, void* d_ws, size_t ws_size,
                              hipStream_t stream) {
    const float* emb  = (const float*)d_in[0];
    const float* W_ih = (const float*)d_in[1];
    const float* W_hh = (const float*)d_in[2];
    const float* b_ih = (const float*)d_in[3];
    const float* b_hh = (const float*)d_in[4];
    float* out = (float*)d_out;

    char* wsb = (char*)d_ws;
    __bf16* BpH  = (__bf16*)(wsb);              // 196608 * 2 B
    __bf16* BpL  = (__bf16*)(wsb + 393216);     // 196608 * 2 B
    float*  biasP = (float*)(wsb + 786432);     // 512 * 4 B
    float*  base  = (float*)(wsb + 1048576);
    const size_t BUF = (size_t)131072 * 128;
    float* hbuf[2] = { base, base + BUF };
    float* cbuf[2] = { base + 2 * BUF, base + 3 * BUF };
    if (ws_size < 1048576 + 4 * BUF * sizeof(float)) return;

    pack_weights<<<768, 256, 0, stream>>>(W_ih, W_hh, b_ih, b_hh, BpH, BpL, biasP);

    int wr = 0;
    for (int d = 17; d >= 0; --d) {
        int n = 1 << d;
        int isTop = (d == 17);
        const float* hin = isTop ? nullptr : hbuf[wr ^ 1];
        const float* cin = isTop ? nullptr : cbuf[wr ^ 1];
        float* ho = (d == 0) ? out : hbuf[wr];
        float* co = (d == 0) ? out + HID : cbuf[wr];
        dim3 grid((n + TM - 1) / TM, 4);
        level_mfma<<<grid, 256, 0, stream>>>(emb, BpH, BpL, biasP, hin, cin, ho, co, n, isTop);
        wr ^= 1;
    }
}

// Round 3
// 638.730 us; speedup vs baseline: 3.7051x; 1.2325x over previous
//
#include <hip/hip_runtime.h>
#include <math.h>

// BinaryTreeLSTM — round 3: single-fp16 MFMA, conflict-free LDS, async B copy.
//  * fp16 inputs to mfma_f32_16x16x32_f16 (fp32 accumulate). Error budget:
//    2^-11 relative per operand, sqrt(K=384) accumulation, sigmoid(f)~0.5
//    damping of the carried c error -> ~1e-3 final vs 1.27e-2 threshold.
//  * h stored fp16 by the epilogue (it is only ever a GEMM input);
//    c stays fp32 (precision-critical carry, elementwise-only consumer).
//  * LDS layout [kq][row|col][8 fp16] = 16B granules, 4-bank stride ->
//    no above-floor bank serialization on ds_read_b128 / ds_write_b128.
//  * B pre-packed in exactly the LDS order -> staged with
//    global_load_lds width=16 (wave-uniform LDS base + lane*16).
//  * grid = (by=4, rowblocks): the 4 sibling blocks sharing an A-tile are
//    adjacent in dispatch order -> A's x4 re-read is L2-resident.

typedef _Float16 f16;
typedef f16 f16x8 __attribute__((ext_vector_type(8)));
typedef float f32x4 __attribute__((ext_vector_type(4)));

#define TM 128
#define HID 128

__device__ __forceinline__ float sigf(float x) { return 1.f / (1.f + __expf(-x)); }
__device__ __forceinline__ float tanh_fast(float x) { return 1.f - 2.f / (1.f + __expf(2.f * x)); }

__device__ __forceinline__ void load_lds_16(const void* g, void* l) {
    __builtin_amdgcn_global_load_lds(
        (const __attribute__((address_space(1))) unsigned int*)g,
        (__attribute__((address_space(3))) unsigned int*)l, 16, 0, 0);
}

// Bp fp16, fragment-order: idx = ((by*12+kci)*4 + kq)*1024 + c*8 + k8,
// c = g*32 + jl; orig row = g*256 + by*32 + jl; orig k = kci*32 + kq*8 + k8.
__global__ __launch_bounds__(256) void pack_weights(
    const float* __restrict__ W_ih, const float* __restrict__ W_hh,
    const float* __restrict__ b_ih, const float* __restrict__ b_hh,
    f16* __restrict__ Bp, float* __restrict__ biasP)
{
    int idx = blockIdx.x * 256 + threadIdx.x;
    if (idx < 196608) {
        int by = idx / 49152;
        int r1 = idx - by * 49152;
        int kci = r1 >> 12;
        int r2 = r1 & 4095;
        int kq = r2 >> 10;
        int r3 = r2 & 1023;
        int c = r3 >> 3;
        int k8 = r3 & 7;
        int g = c >> 5, jl = c & 31;
        int rOrig = g * 256 + by * 32 + jl;
        int kk = kci * 32 + kq * 8 + k8;
        float w = (kk < 128) ? W_ih[(size_t)rOrig * 128 + kk]
                             : W_hh[(size_t)rOrig * 256 + (kk - 128)];
        Bp[idx] = (f16)w;
    }
    if (idx < 512) {
        int by = idx >> 7, c = idx & 127;
        int g = c >> 5, jl = c & 31;
        int rOrig = g * 256 + by * 32 + jl;
        biasP[idx] = b_ih[rOrig] + b_hh[rOrig];
    }
}

__global__ __launch_bounds__(256) void level_mfma(
    const float* __restrict__ emb,
    const f16* __restrict__ Bp, const float* __restrict__ biasP,
    const f16* __restrict__ h_in,    // child h: (2n,128) fp16 = (n,256) flat
    const float* __restrict__ c_in,  // child c: (2n,128) fp32
    f16* __restrict__ h_out,         // (n,128) fp16
    float* __restrict__ c_out,       // (n,128) fp32
    float* __restrict__ root_out,    // non-null only at d==0: [h(128)|c(128)] fp32
    int n, int isTop)
{
    __shared__ __align__(16) f16 As[4][TM][8];   // [kq][row][8k] 8 KB
    __shared__ __align__(16) f16 Bs[4][128][8];  // [kq][col][8k] 8 KB

    const int tid = threadIdx.x;
    const int lane = tid & 63;
    const int w = tid >> 6;
    const int wm = w & 1, wn = w >> 1;
    const int by = blockIdx.x;          // 0..3 — N-slice (32 output cols)
    const int row0 = blockIdx.y * TM;
    const int l15 = lane & 15;
    const int kq = lane >> 4;
    const int sm = tid >> 1;            // staging row 0..127
    const int sh = tid & 1;             // staging k-half (16 elems)

    f32x4 acc[4][4];
    #pragma unroll
    for (int a = 0; a < 4; ++a)
        #pragma unroll
        for (int b = 0; b < 4; ++b) acc[a][b] = (f32x4)0.f;

    const int nch = isTop ? 4 : 12;
    for (int kci = 0; kci < nch; ++kci) {
        // ---- B chunk (8 KB): async DMA, straight copy of pre-packed data ----
        {
            const char* gb = (const char*)Bp + (((size_t)(by * 12 + kci)) << 13);
            char* lb = (char*)&Bs[0][0][0];
            size_t s0 = (size_t)w * 2048;
            load_lds_16(gb + s0 + (size_t)lane * 16, lb + s0);
            load_lds_16(gb + s0 + 1024 + (size_t)lane * 16, lb + s0 + 1024);
        }
        // ---- A chunk (8 KB): emb fp32->fp16 (phase 1) or h fp16 copy ----
        {
            int node = row0 + sm;
            f16 av[16];
            if (node >= n) {
                #pragma unroll
                for (int i = 0; i < 16; ++i) av[i] = (f16)0.f;
            } else if (kci < 4) {
                const float* p = emb + (size_t)(n - 1 + node) * 128 + kci * 32 + sh * 16;
                float4 f0 = *(const float4*)(p + 0);
                float4 f1 = *(const float4*)(p + 4);
                float4 f2 = *(const float4*)(p + 8);
                float4 f3 = *(const float4*)(p + 12);
                av[0] = (f16)f0.x; av[1] = (f16)f0.y; av[2] = (f16)f0.z; av[3] = (f16)f0.w;
                av[4] = (f16)f1.x; av[5] = (f16)f1.y; av[6] = (f16)f1.z; av[7] = (f16)f1.w;
                av[8] = (f16)f2.x; av[9] = (f16)f2.y; av[10] = (f16)f2.z; av[11] = (f16)f2.w;
                av[12] = (f16)f3.x; av[13] = (f16)f3.y; av[14] = (f16)f3.z; av[15] = (f16)f3.w;
            } else {
                const f16* p = h_in + (size_t)node * 256 + (kci - 4) * 32 + sh * 16;
                *(f16x8*)&av[0] = *(const f16x8*)p;
                *(f16x8*)&av[8] = *(const f16x8*)(p + 8);
            }
            *(f16x8*)&As[sh * 2 + 0][sm][0] = *(f16x8*)&av[0];
            *(f16x8*)&As[sh * 2 + 1][sm][0] = *(f16x8*)&av[8];
        }
        __syncthreads();

        // ---- fragments (conflict-free b128) + 16 MFMAs ----
        f16x8 af[4], bfr[4];
        #pragma unroll
        for (int mi = 0; mi < 4; ++mi)
            af[mi] = *(const f16x8*)&As[kq][wm * 64 + mi * 16 + l15][0];
        #pragma unroll
        for (int g = 0; g < 4; ++g)
            bfr[g] = *(const f16x8*)&Bs[kq][g * 32 + wn * 16 + l15][0];
        #pragma unroll
        for (int mi = 0; mi < 4; ++mi)
            #pragma unroll
            for (int g = 0; g < 4; ++g)
                acc[mi][g] = __builtin_amdgcn_mfma_f32_16x16x32_f16(
                    af[mi], bfr[g], acc[mi][g], 0, 0, 0);
        __syncthreads();
    }

    // ---- Epilogue: i,f,g,o register-local; h fp16, c fp32 ----
    const int jl32 = wn * 16 + l15;
    const int j = by * 32 + jl32;
    const float bi = biasP[by * 128 + 0 * 32 + jl32];
    const float bfv = biasP[by * 128 + 1 * 32 + jl32];
    const float bg = biasP[by * 128 + 2 * 32 + jl32];
    const float bo = biasP[by * 128 + 3 * 32 + jl32];
    const int isRoot = (root_out != nullptr);
    #pragma unroll
    for (int mi = 0; mi < 4; ++mi) {
        #pragma unroll
        for (int r = 0; r < 4; ++r) {
            int node = row0 + wm * 64 + mi * 16 + kq * 4 + r;
            if (node < n) {
                float gi = acc[mi][0][r] + bi;
                float gf = acc[mi][1][r] + bfv;
                float gg = acc[mi][2][r] + bg;
                float go = acc[mi][3][r] + bo;
                float cl = isTop ? 0.f : c_in[(size_t)node * 256 + j]; // left child c
                float cn = sigf(gf) * cl + sigf(gi) * tanh_fast(gg);
                float hn = sigf(go) * tanh_fast(cn);
                if (isRoot) {
                    root_out[j] = hn;
                    root_out[128 + j] = cn;
                } else {
                    h_out[(size_t)node * 128 + j] = (f16)hn;
                    c_out[(size_t)node * 128 + j] = cn;
                }
            }
        }
    }
}

extern "C" void kernel_launch(void* const* d_in, const int* in_sizes, int n_in,
                              void* d_out, int out_size, void* d_ws, size_t ws_size,
                              hipStream_t stream) {
    const float* emb  = (const float*)d_in[0];
    const float* W_ih = (const float*)d_in[1];
    const float* W_hh = (const float*)d_in[2];
    const float* b_ih = (const float*)d_in[3];
    const float* b_hh = (const float*)d_in[4];

    char* wsb = (char*)d_ws;
    f16*   Bp    = (f16*)wsb;                    // 393216 B
    float* biasP = (float*)(wsb + 393216);       // 2048 B
    char*  bufs  = wsb + 1048576;
    const size_t HBUF = (size_t)131072 * 128 * sizeof(f16);   // 32 MiB
    const size_t CBUF = (size_t)131072 * 128 * sizeof(float); // 64 MiB
    f16* hbuf[2]   = { (f16*)bufs, (f16*)(bufs + HBUF) };
    float* cbuf[2] = { (float*)(bufs + 2 * HBUF), (float*)(bufs + 2 * HBUF + CBUF) };
    if (ws_size < 1048576 + 2 * HBUF + 2 * CBUF) return;

    pack_weights<<<768, 256, 0, stream>>>(W_ih, W_hh, b_ih, b_hh, Bp, biasP);

    int wr = 0;
    for (int d = 17; d >= 0; --d) {
        int n = 1 << d;
        int isTop = (d == 17);
        const f16* hin   = isTop ? nullptr : hbuf[wr ^ 1];
        const float* cin = isTop ? nullptr : cbuf[wr ^ 1];
        float* root = (d == 0) ? (float*)d_out : nullptr;
        dim3 grid(4, (n + TM - 1) / TM);
        level_mfma<<<grid, 256, 0, stream>>>(emb, Bp, biasP, hin, cin,
                                             hbuf[wr], cbuf[wr], root, n, isTop);
        wr ^= 1;
    }
}